// Round 6
// baseline (149.744 us; speedup 1.0000x reference)
//
#include <hip/hip_runtime.h>
#include <hip/hip_bf16.h>
#include <math.h>

typedef __bf16 bf16x8 __attribute__((ext_vector_type(8)));
typedef float  f32x4  __attribute__((ext_vector_type(4)));

#define B_    2
#define N_    2048
#define H_    16
#define D_    64
#define HD    (H_ * D_)
#define QSCALE (0.125f * 1.44269504089f)   // 1/sqrt(64) * log2(e)
#define THR   8.0f
#define NT    32                            // kv tiles of 64
#define TILE_BYTES 16384                    // K 8KB + V 8KB per tile (bf16)
#define BH_BYTES ((size_t)NT * TILE_BYTES)  // 512 KB per (b,h)
#define WS_NEED ((size_t)B_ * H_ * BH_BYTES)

#if __has_builtin(__builtin_amdgcn_exp2f)
#define EXP2F(x) __builtin_amdgcn_exp2f(x)
#else
#define EXP2F(x) __expf(0.69314718056f * (x))
#endif

// ---------------- prep: K -> bf16 tiles [row n][d16] LINEAR; V -> bf16 [row d][n16] LINEAR ----
// No swizzle here (fully coalesced writes); the T2 XOR is applied by the attn kernel's
// staging SOURCE address (LDS dest linear, involution -> same ds_read swizzle works).
__global__ __launch_bounds__(256) void prep_kv(
    const float* __restrict__ k, const float* __restrict__ v,
    char* __restrict__ ws)
{
    __shared__ float tile[64][69];   // stride 69: 8-row column reads land on 4 banks x2 (free)
    const int tid = threadIdx.x;
    const int bid = blockIdx.x;

    if (bid < 2048) {
        // ---- K: one 16B chunk per thread, reads & writes fully coalesced ----
        int g   = bid * 256 + tid;        // global K chunk id, 524288 total
        int bh  = g >> 14;                // 16384 K-chunks per (b,h)
        int rem = g & 16383;
        int t   = rem >> 9;
        int c   = rem & 511;              // chunk within tile: row n (c>>3), d16 (c&7)
        int n   = c >> 3, d16 = c & 7;
        int b = bh >> 4, h = bh & 15;
        const float* s = k + ((size_t)(b * N_ + t * 64 + n) * H_ + h) * D_ + d16 * 8;
        f32x4 a0 = *(const f32x4*)s;
        f32x4 a1 = *(const f32x4*)(s + 4);
        bf16x8 o;
        #pragma unroll
        for (int j = 0; j < 4; ++j) { o[j] = (__bf16)a0[j]; o[4 + j] = (__bf16)a1[j]; }
        *(bf16x8*)(ws + (size_t)bh * BH_BYTES + (size_t)t * TILE_BYTES + c * 16) = o;
    } else {
        // ---- V: one (bh, tile) per block; transpose via LDS; linear coalesced writes ----
        int vb = bid - 2048;
        int bh = vb >> 5, t = vb & 31;
        int b = bh >> 4, h = bh & 15;
        #pragma unroll
        for (int rep = 0; rep < 4; ++rep) {
            int idx = rep * 256 + tid;
            int i = idx >> 4, c4 = (idx & 15) * 4;
            *(f32x4*)&tile[i][c4] =
                *(const f32x4*)(v + ((size_t)(b * N_ + t * 64 + i) * H_ + h) * D_ + c4);
        }
        __syncthreads();
        char* dst = ws + (size_t)bh * BH_BYTES + (size_t)t * TILE_BYTES + 8192;
        #pragma unroll
        for (int rep = 0; rep < 2; ++rep) {
            int c = rep * 256 + tid;
            int d = c >> 3, n16 = c & 7;
            bf16x8 o;
            #pragma unroll
            for (int j = 0; j < 8; ++j) o[j] = (__bf16)tile[n16 * 8 + j][d];
            *(bf16x8*)(dst + c * 16) = o;
        }
    }
}

// ---------------- main: 8 waves x 32 q-rows (QBLK=256), LDS double-buffered K/V ----------
__global__ __launch_bounds__(512, 2) void attn_fwd_v5(
    const float* __restrict__ q,     // original [b][n][h][d] fp32
    const char* __restrict__ ws,     // linear bf16 K/V tiles
    float* __restrict__ out)
{
    const int tid  = threadIdx.x;
    const int lane = tid & 63;
    const int w    = tid >> 6;       // wave 0..7
    const int lo   = lane & 15;
    const int hi   = lane >> 4;

    // bijective XCD swizzle: 256 blocks = 8 XCDs x 32; each XCD owns 4 (b,h)
    int bid = blockIdx.x;
    int wg  = (bid & 7) * 32 + (bid >> 3);
    int qt  = wg & 7;                 // 8 q-tiles of 256 rows
    int bh  = wg >> 3;
    int h   = bh & 15;
    int b   = bh >> 4;

    __shared__ __align__(16) char kv_lds[2][TILE_BYTES];
    __shared__ __align__(16) __bf16 p_lds[8][16][72];

    const char* wsrc = ws + (size_t)bh * BH_BYTES;
    const int q0 = qt * 256 + w * 32;

    // staging map: thread owns LDS chunks tid and tid+512 (linear dest);
    // source chunk pre-XORed so LDS content is T2-swizzled for conflict-free ds_read
    const int srow = tid >> 3, scol = tid & 7;
    const int src0 = (srow * 8 + (scol ^ (srow & 7))) * 16;  // K half
    const int src1 = src0 + 8192;                            // V half (same row/col map)
    const int ldso0 = tid * 16, ldso1 = tid * 16 + 8192;

    // Q: fp32 direct load, convert+scale inline (read once)
    bf16x8 qa[2][2];
    #pragma unroll
    for (int rb = 0; rb < 2; ++rb)
        #pragma unroll
        for (int kk = 0; kk < 2; ++kk) {
            const float* qs = q + ((size_t)(b * N_ + q0 + rb * 16 + lo) * H_ + h) * D_ + kk * 32 + hi * 8;
            f32x4 a0 = *(const f32x4*)qs;
            f32x4 a1 = *(const f32x4*)(qs + 4);
            #pragma unroll
            for (int j = 0; j < 4; ++j) {
                qa[rb][kk][j]     = (__bf16)(a0[j] * QSCALE);
                qa[rb][kk][4 + j] = (__bf16)(a1[j] * QSCALE);
            }
        }

    float m[2][4], l[2][4];
    f32x4 o[2][4];
    #pragma unroll
    for (int rb = 0; rb < 2; ++rb)
        #pragma unroll
        for (int r = 0; r < 4; ++r) { m[rb][r] = -INFINITY; l[rb][r] = 0.f; }
    #pragma unroll
    for (int rb = 0; rb < 2; ++rb)
        #pragma unroll
        for (int f = 0; f < 4; ++f) o[rb][f] = (f32x4)0.f;

    {   // prologue: stage tile 0
        bf16x8 s0 = *(const bf16x8*)(wsrc + src0);
        bf16x8 s1 = *(const bf16x8*)(wsrc + src1);
        *(bf16x8*)(kv_lds[0] + ldso0) = s0;
        *(bf16x8*)(kv_lds[0] + ldso1) = s1;
    }
    __syncthreads();

    for (int t = 0; t < NT; ++t) {
        const char* kbuf = kv_lds[t & 1];
        const char* vbuf = kbuf + 8192;

        // issue next-tile stage loads first (L2 latency hides under compute)
        const size_t tb = (size_t)((t + 1) & (NT - 1)) * TILE_BYTES;
        bf16x8 s0 = *(const bf16x8*)(wsrc + tb + src0);
        bf16x8 s1 = *(const bf16x8*)(wsrc + tb + src1);

        // K frags read ONCE, feed both row-blocks (2 independent MFMA chains)
        f32x4 sc[2][4];
        #pragma unroll
        for (int rb = 0; rb < 2; ++rb)
            #pragma unroll
            for (int c = 0; c < 4; ++c) sc[rb][c] = (f32x4)0.f;
        #pragma unroll
        for (int c = 0; c < 4; ++c)
            #pragma unroll
            for (int kk = 0; kk < 2; ++kk) {
                int row = c * 16 + lo;
                int d16 = kk * 4 + hi;
                bf16x8 kf = *(const bf16x8*)(kbuf + row * 128 + ((d16 ^ (row & 7)) << 4));
                sc[0][c] = __builtin_amdgcn_mfma_f32_16x16x32_bf16(qa[0][kk], kf, sc[0][c], 0, 0, 0);
                sc[1][c] = __builtin_amdgcn_mfma_f32_16x16x32_bf16(qa[1][kk], kf, sc[1][c], 0, 0, 0);
            }
        // V frags read ONCE for both row-blocks
        bf16x8 vf[4][2];
        #pragma unroll
        for (int f = 0; f < 4; ++f)
            #pragma unroll
            for (int s2 = 0; s2 < 2; ++s2) {
                int row = f * 16 + lo;
                int n16 = s2 * 4 + hi;
                vf[f][s2] = *(const bf16x8*)(vbuf + row * 128 + ((n16 ^ (row & 7)) << 4));
            }

        #pragma unroll
        for (int rb = 0; rb < 2; ++rb) {
            // online softmax, exp2 domain, T13 defer-max
            float pm[4];
            #pragma unroll
            for (int r = 0; r < 4; ++r)
                pm[r] = fmaxf(fmaxf(sc[rb][0][r], sc[rb][1][r]), fmaxf(sc[rb][2][r], sc[rb][3][r]));
            int ok = (pm[0] <= m[rb][0] + THR) & (pm[1] <= m[rb][1] + THR)
                   & (pm[2] <= m[rb][2] + THR) & (pm[3] <= m[rb][3] + THR);
            if (!__all(ok)) {
                #pragma unroll
                for (int r = 0; r < 4; ++r) {
                    float tmax = pm[r];
                    #pragma unroll
                    for (int msk = 1; msk <= 8; msk <<= 1)
                        tmax = fmaxf(tmax, __shfl_xor(tmax, msk, 64));
                    float mn = fmaxf(m[rb][r], tmax);
                    float a  = EXP2F(m[rb][r] - mn);
                    m[rb][r] = mn;
                    l[rb][r] *= a;
                    #pragma unroll
                    for (int f = 0; f < 4; ++f) o[rb][f][r] *= a;
                }
            }
            #pragma unroll
            for (int r = 0; r < 4; ++r) {
                float p0 = EXP2F(sc[rb][0][r] - m[rb][r]);
                float p1 = EXP2F(sc[rb][1][r] - m[rb][r]);
                float p2 = EXP2F(sc[rb][2][r] - m[rb][r]);
                float p3 = EXP2F(sc[rb][3][r] - m[rb][r]);
                l[rb][r] += (p0 + p1) + (p2 + p3);
                p_lds[w][hi * 4 + r][lo]      = (__bf16)p0;
                p_lds[w][hi * 4 + r][16 + lo] = (__bf16)p1;
                p_lds[w][hi * 4 + r][32 + lo] = (__bf16)p2;
                p_lds[w][hi * 4 + r][48 + lo] = (__bf16)p3;
            }
            // wave-synchronous P transpose (wave-private buffer, in-order LDS pipe)
            __asm__ volatile("" ::: "memory");
            bf16x8 pa0 = *(const bf16x8*)&p_lds[w][lo][hi * 8];
            bf16x8 pa1 = *(const bf16x8*)&p_lds[w][lo][32 + hi * 8];
            __asm__ volatile("" ::: "memory");
            #pragma unroll
            for (int f = 0; f < 4; ++f) {
                o[rb][f] = __builtin_amdgcn_mfma_f32_16x16x32_bf16(pa0, vf[f][0], o[rb][f], 0, 0, 0);
                o[rb][f] = __builtin_amdgcn_mfma_f32_16x16x32_bf16(pa1, vf[f][1], o[rb][f], 0, 0, 0);
            }
        }

        // write staged regs into the other LDS buffer; one barrier per tile
        *(bf16x8*)(kv_lds[(t + 1) & 1] + ldso0) = s0;
        *(bf16x8*)(kv_lds[(t + 1) & 1] + ldso1) = s1;
        __syncthreads();
    }

    // epilogue: reduce deferred l across 16 row-lanes, normalize, store
    float* op = out + (size_t)b * N_ * HD + (size_t)h * D_;
    #pragma unroll
    for (int rb = 0; rb < 2; ++rb)
        #pragma unroll
        for (int r = 0; r < 4; ++r) {
            float rs = l[rb][r];
            #pragma unroll
            for (int msk = 1; msk <= 8; msk <<= 1)
                rs += __shfl_xor(rs, msk, 64);
            float rinv = 1.f / rs;
            float* orow = op + (size_t)(q0 + rb * 16 + hi * 4 + r) * HD;
            #pragma unroll
            for (int f = 0; f < 4; ++f)
                orow[f * 16 + lo] = o[rb][f][r] * rinv;
        }
}

// ---------------- fallback (fp32 direct) if workspace too small ----------
__global__ __launch_bounds__(256) void attn_fwd_v1(
    const float* __restrict__ q, const float* __restrict__ k,
    const float* __restrict__ v, float* __restrict__ out)
{
    const int tid  = threadIdx.x;
    const int lane = tid & 63;
    const int w    = tid >> 6;
    const int lo   = lane & 15;
    const int hi   = lane >> 4;
    const int qt   = blockIdx.x;
    const int h    = blockIdx.y;
    const int b    = blockIdx.z;

    __shared__ __align__(16) __bf16 p_lds[4][16][40];

    const size_t bh_off = (size_t)b * N_ * HD + (size_t)h * D_;
    const float* qp = q + bh_off;
    const float* kp = k + bh_off;
    const float* vp = v + bh_off;
    float*       op = out + bh_off;

    const int q0 = qt * 64 + w * 16;

    bf16x8 qa[2];
    {
        const float* qrow = qp + (size_t)(q0 + lo) * HD + hi * 8;
        #pragma unroll
        for (int kk = 0; kk < 2; ++kk)
            #pragma unroll
            for (int j = 0; j < 8; ++j)
                qa[kk][j] = (__bf16)(qrow[kk * 32 + j] * 0.125f);
    }

    float m[4], l[4];
    f32x4 o[4];
    #pragma unroll
    for (int r = 0; r < 4; ++r) { m[r] = -INFINITY; l[r] = 0.f; }
    #pragma unroll
    for (int f = 0; f < 4; ++f) o[f] = (f32x4)0.f;

    for (int kv0 = 0; kv0 < N_; kv0 += 32) {
        f32x4 s[2];
        #pragma unroll
        for (int c = 0; c < 2; ++c) {
            s[c] = (f32x4)0.f;
            const float* krow = kp + (size_t)(kv0 + c * 16 + lo) * HD + hi * 8;
            #pragma unroll
            for (int kk = 0; kk < 2; ++kk) {
                bf16x8 kbv;
                #pragma unroll
                for (int j = 0; j < 8; ++j) kbv[j] = (__bf16)krow[kk * 32 + j];
                s[c] = __builtin_amdgcn_mfma_f32_16x16x32_bf16(qa[kk], kbv, s[c], 0, 0, 0);
            }
        }
        float alpha[4], p0[4], p1[4];
        #pragma unroll
        for (int r = 0; r < 4; ++r) {
            float t = fmaxf(s[0][r], s[1][r]);
            #pragma unroll
            for (int msk = 1; msk <= 8; msk <<= 1) t = fmaxf(t, __shfl_xor(t, msk, 64));
            float mn = fmaxf(m[r], t);
            alpha[r] = __expf(m[r] - mn);
            p0[r] = __expf(s[0][r] - mn);
            p1[r] = __expf(s[1][r] - mn);
            float rs = p0[r] + p1[r];
            #pragma unroll
            for (int msk = 1; msk <= 8; msk <<= 1) rs += __shfl_xor(rs, msk, 64);
            l[r] = l[r] * alpha[r] + rs;
            m[r] = mn;
        }
        #pragma unroll
        for (int f = 0; f < 4; ++f)
            #pragma unroll
            for (int r = 0; r < 4; ++r) o[f][r] *= alpha[r];
        #pragma unroll
        for (int r = 0; r < 4; ++r) {
            p_lds[w][hi * 4 + r][lo]      = (__bf16)p0[r];
            p_lds[w][hi * 4 + r][16 + lo] = (__bf16)p1[r];
        }
        __syncthreads();
        bf16x8 pa = *(const bf16x8*)&p_lds[w][lo][hi * 8];
        #pragma unroll
        for (int f = 0; f < 4; ++f) {
            const float* vrow = vp + (size_t)(kv0 + hi * 8) * HD + f * 16 + lo;
            bf16x8 vb;
            #pragma unroll
            for (int j = 0; j < 8; ++j) vb[j] = (__bf16)vrow[(size_t)j * HD];
            o[f] = __builtin_amdgcn_mfma_f32_16x16x32_bf16(pa, vb, o[f], 0, 0, 0);
        }
        __syncthreads();
    }
    #pragma unroll
    for (int r = 0; r < 4; ++r) {
        float rinv = 1.f / l[r];
        float* orow = op + (size_t)(q0 + hi * 4 + r) * HD;
        #pragma unroll
        for (int f = 0; f < 4; ++f) orow[f * 16 + lo] = o[f][r] * rinv;
    }
}

extern "C" void kernel_launch(void* const* d_in, const int* in_sizes, int n_in,
                              void* d_out, int out_size, void* d_ws, size_t ws_size,
                              hipStream_t stream)
{
    const float* q = (const float*)d_in[0];
    const float* k = (const float*)d_in[1];
    const float* v = (const float*)d_in[2];
    float* out = (float*)d_out;

    if (ws_size >= WS_NEED) {
        char* ws = (char*)d_ws;
        prep_kv<<<dim3(3072), 256, 0, stream>>>(k, v, ws);
        attn_fwd_v5<<<dim3(256), 512, 0, stream>>>(q, ws, out);
    } else {
        attn_fwd_v1<<<dim3(N_ / 64, H_, B_), 256, 0, stream>>>(q, k, v, out);
    }
}

// Round 7
// 141.979 us; speedup vs baseline: 1.0547x; 1.0547x over previous
//
#include <hip/hip_runtime.h>
#include <hip/hip_bf16.h>
#include <math.h>

typedef __bf16 bf16x8 __attribute__((ext_vector_type(8)));
typedef float  f32x4  __attribute__((ext_vector_type(4)));
typedef float  f32x16 __attribute__((ext_vector_type(16)));

#define B_    2
#define N_    2048
#define H_    16
#define D_    64
#define HD    (H_ * D_)
#define QSCALE (0.125f * 1.44269504089f)   // 1/sqrt(64) * log2(e): exp2 domain
#define THR   8.0f
#define NT    32                            // kv tiles of 64 rows
#define VT_BYTES 8192                       // one V^T tile (64 d x 64 n bf16)
#define WS_NEED ((size_t)B_ * H_ * NT * VT_BYTES)   // 8.4 MB

#if __has_builtin(__builtin_amdgcn_exp2f)
#define EXP2F(x) __builtin_amdgcn_exp2f(x)
#else
#define EXP2F(x) __expf(0.69314718056f * (x))
#endif

__device__ __forceinline__ unsigned pk2(float a, float b) {
    union { __bf16 h[2]; unsigned u; } t;
    t.h[0] = (__bf16)a; t.h[1] = (__bf16)b;
    return t.u;
}

// ---------------- prep: V -> bf16 transposed tiles [bh][t][row d][chunk n16], LINEAR ----
__global__ __launch_bounds__(256) void prep_v(
    const float* __restrict__ v, char* __restrict__ ws)
{
    __shared__ float tile[64][69];
    const int tid = threadIdx.x;
    const int vb  = blockIdx.x;           // 1024 = 32 bh x 32 tiles
    const int bh  = vb >> 5, t = vb & 31;
    const int b = bh >> 4, h = bh & 15;

    #pragma unroll
    for (int rep = 0; rep < 4; ++rep) {
        int idx = rep * 256 + tid;
        int i = idx >> 4, c4 = (idx & 15) * 4;
        *(f32x4*)&tile[i][c4] =
            *(const f32x4*)(v + ((size_t)(b * N_ + t * 64 + i) * H_ + h) * D_ + c4);
    }
    __syncthreads();
    char* dst = ws + ((size_t)bh * NT + t) * VT_BYTES;
    #pragma unroll
    for (int rep = 0; rep < 2; ++rep) {
        int c = rep * 256 + tid;
        int d = c >> 3, n16 = c & 7;
        bf16x8 o;
        #pragma unroll
        for (int j = 0; j < 8; ++j) o[j] = (__bf16)tile[n16 * 8 + j][d];
        *(bf16x8*)(dst + c * 16) = o;
    }
}

// ---------------- main: swapped-QK^T flash attention, in-register softmax ----------
// 8 waves x 32 q-rows (QBLK=256). Lane owns q-row q0+(lane&31); hi=lane>>5 splits k.
__global__ __launch_bounds__(512, 2) void attn_fwd_v6(
    const float* __restrict__ q,     // [b][n][h][d] fp32
    const float* __restrict__ k,     // [b][n][h][d] fp32 (converted inline)
    const char*  __restrict__ vws,   // V^T bf16 tiles
    float* __restrict__ out)
{
    const int tid  = threadIdx.x;
    const int lane = tid & 63;
    const int w    = tid >> 6;
    const int lo   = lane & 31;
    const int hi   = lane >> 5;
    const bool hib = hi != 0;

    // bijective XCD swizzle: 256 blocks = 8 XCDs x 32; each XCD owns 4 (b,h)
    int bid = blockIdx.x;
    int wg  = (bid & 7) * 32 + (bid >> 3);
    int qt  = wg & 7;
    int bh  = wg >> 3;
    int h   = bh & 15;
    int b   = bh >> 4;

    __shared__ __align__(16) char kv_lds[2][16384];   // [K 8KB | V^T 8KB] x2

    const int q0 = qt * 256 + w * 32;
    const int qr = q0 + lo;                 // this lane's q-row

    // Q B-frags: lane holds Q[qr][ds*16 + hi*8 + j], j=0..7, pre-scaled
    bf16x8 qb[4];
    #pragma unroll
    for (int ds = 0; ds < 4; ++ds) {
        const float* qs = q + ((size_t)(b * N_ + qr) * H_ + h) * D_ + ds * 16 + hi * 8;
        f32x4 a0 = *(const f32x4*)qs;
        f32x4 a1 = *(const f32x4*)(qs + 4);
        #pragma unroll
        for (int j = 0; j < 4; ++j) {
            qb[ds][j]     = (__bf16)(a0[j] * QSCALE);
            qb[ds][4 + j] = (__bf16)(a1[j] * QSCALE);
        }
    }

    // staging maps: thread owns one 16B chunk (row sn, chunk sd) of each half
    const int sn = tid >> 3, sd = tid & 7;
    const float* ksrc = k + ((size_t)(b * N_ + sn) * H_ + h) * D_ + sd * 8;
    const int   kdst  = (sn * 8 + (sd ^ (sn & 7))) * 16;       // swizzled LDS dest
    const char* vbase = vws + (size_t)bh * NT * VT_BYTES;
    const int   vsrc  = (sn * 8 + (sd ^ (sn & 7))) * 16;       // src-XOR, linear dest
    const int   vdst  = tid * 16;

    float m = -INFINITY, l = 0.f;
    f32x16 ov0 = (f32x16)0.f, ov1 = (f32x16)0.f;

    {   // prologue: stage tile 0
        f32x4 kg0 = *(const f32x4*)ksrc;
        f32x4 kg1 = *(const f32x4*)(ksrc + 4);
        bf16x8 vg = *(const bf16x8*)(vbase + vsrc);
        bf16x8 kc;
        #pragma unroll
        for (int j = 0; j < 4; ++j) { kc[j] = (__bf16)kg0[j]; kc[4 + j] = (__bf16)kg1[j]; }
        *(bf16x8*)(kv_lds[0] + kdst) = kc;
        *(bf16x8*)(kv_lds[0] + 8192 + vdst) = vg;
    }
    __syncthreads();

    for (int t = 0; t < NT; ++t) {
        const char* cur = kv_lds[t & 1];
        char* nxt = kv_lds[(t + 1) & 1];

        // issue next-tile global loads (full tile of compute to cover latency)
        const int tn = (t + 1) & (NT - 1);
        f32x4 kg0 = *(const f32x4*)(ksrc + (size_t)tn * 64 * HD);
        f32x4 kg1 = *(const f32x4*)(ksrc + (size_t)tn * 64 * HD + 4);
        bf16x8 vg = *(const bf16x8*)(vbase + (size_t)tn * VT_BYTES + vsrc);

        // ---- QK^T swapped: S^T[k][q], two 32x32 tiles over k ----
        f32x16 sc0 = (f32x16)0.f, sc1 = (f32x16)0.f;
        __builtin_amdgcn_s_setprio(1);
        #pragma unroll
        for (int ds = 0; ds < 4; ++ds) {
            int row0 = lo;          // k-rows 0..31
            int row1 = 32 + lo;     // k-rows 32..63
            bf16x8 ka0 = *(const bf16x8*)(cur + row0 * 128 + (((2 * ds + hi) ^ (row0 & 7)) << 4));
            bf16x8 ka1 = *(const bf16x8*)(cur + row1 * 128 + (((2 * ds + hi) ^ (row1 & 7)) << 4));
            sc0 = __builtin_amdgcn_mfma_f32_32x32x16_bf16(ka0, qb[ds], sc0, 0, 0, 0);
            sc1 = __builtin_amdgcn_mfma_f32_32x32x16_bf16(ka1, qb[ds], sc1, 0, 0, 0);
        }
        __builtin_amdgcn_s_setprio(0);

        // ---- row max (all in-register: lane holds 32 of 64 k for its q-row) ----
        float t8[8];
        #pragma unroll
        for (int e = 0; e < 8; ++e)
            t8[e] = fmaxf(fmaxf(sc0[e], sc0[e + 8]), fmaxf(sc1[e], sc1[e + 8]));
        float pm = fmaxf(fmaxf(fmaxf(t8[0], t8[1]), fmaxf(t8[2], t8[3])),
                         fmaxf(fmaxf(t8[4], t8[5]), fmaxf(t8[6], t8[7])));

        // T13 defer-max: rare rescale path
        if (!__all(pm <= m + THR)) {
            float pmf = fmaxf(pm, __shfl_xor(pm, 32, 64));
            float mn  = fmaxf(m, pmf);
            float a   = EXP2F(m - mn);
            m = mn; l *= a;
            #pragma unroll
            for (int reg = 0; reg < 16; ++reg) {
                int qrr = (reg & 3) + 8 * (reg >> 2) + 4 * hi;
                float ar = __int_as_float(
                    __builtin_amdgcn_ds_bpermute(qrr << 2, __float_as_int(a)));
                ov0[reg] *= ar; ov1[reg] *= ar;
            }
        }

        // ---- V^T B-frags (issue before exp section; LDS latency hides under VALU) ----
        bf16x8 vf0[4], vf1[4];
        #pragma unroll
        for (int ks = 0; ks < 4; ++ks) {
            int row0 = lo;          // d 0..31
            int row1 = 32 + lo;     // d 32..63
            vf0[ks] = *(const bf16x8*)(cur + 8192 + row0 * 128 + (((2 * ks + hi) ^ (row0 & 7)) << 4));
            vf1[ks] = *(const bf16x8*)(cur + 8192 + row1 * 128 + (((2 * ks + hi) ^ (row1 & 7)) << 4));
        }

        // ---- P = exp2(S - m), pack to bf16 A-frags with half-wave exchange ----
        union { unsigned u[4]; bf16x8 v; } pa[4];
        #pragma unroll
        for (int ks = 0; ks < 4; ++ks) {
            const int r0 = (ks & 1) * 8;
            float p[8];
            #pragma unroll
            for (int e = 0; e < 8; ++e) {
                float s = (ks < 2) ? ((ks & 1) ? sc0[r0 + e] : sc0[e])
                                   : ((ks & 1) ? sc1[r0 + e] : sc1[e]);
                p[e] = EXP2F(s - m);
            }
            l += ((p[0] + p[1]) + (p[2] + p[3])) + ((p[4] + p[5]) + (p[6] + p[7]));
            unsigned w0 = pk2(p[0], p[1]);
            unsigned w1 = pk2(p[2], p[3]);
            unsigned w2 = pk2(p[4], p[5]);
            unsigned w3 = pk2(p[6], p[7]);
            unsigned w0p = (unsigned)__shfl_xor((int)w0, 32, 64);
            unsigned w1p = (unsigned)__shfl_xor((int)w1, 32, 64);
            unsigned w2p = (unsigned)__shfl_xor((int)w2, 32, 64);
            unsigned w3p = (unsigned)__shfl_xor((int)w3, 32, 64);
            pa[ks].u[0] = hib ? w2p : w0;
            pa[ks].u[1] = hib ? w3p : w1;
            pa[ks].u[2] = hib ? w2  : w0p;
            pa[ks].u[3] = hib ? w3  : w1p;
        }

        // ---- PV: O[q][d] two 32-col tiles ----
        __builtin_amdgcn_s_setprio(1);
        #pragma unroll
        for (int ks = 0; ks < 4; ++ks) {
            ov0 = __builtin_amdgcn_mfma_f32_32x32x16_bf16(pa[ks].v, vf0[ks], ov0, 0, 0, 0);
            ov1 = __builtin_amdgcn_mfma_f32_32x32x16_bf16(pa[ks].v, vf1[ks], ov1, 0, 0, 0);
        }
        __builtin_amdgcn_s_setprio(0);

        // ---- stage next tile into the other buffer; one barrier per tile ----
        bf16x8 kc;
        #pragma unroll
        for (int j = 0; j < 4; ++j) { kc[j] = (__bf16)kg0[j]; kc[4 + j] = (__bf16)kg1[j]; }
        *(bf16x8*)(nxt + kdst) = kc;
        *(bf16x8*)(nxt + 8192 + vdst) = vg;
        __syncthreads();
    }

    // ---- epilogue ----
    float lt = l + __shfl_xor(l, 32, 64);
    float rinv = 1.f / lt;
    #pragma unroll
    for (int reg = 0; reg < 16; ++reg) {
        int qrr = (reg & 3) + 8 * (reg >> 2) + 4 * hi;
        float rv = __int_as_float(
            __builtin_amdgcn_ds_bpermute(qrr << 2, __float_as_int(rinv)));
        float* orow = out + ((size_t)(b * N_ + q0 + qrr) * H_ + h) * D_;
        orow[lo]      = ov0[reg] * rv;
        orow[32 + lo] = ov1[reg] * rv;
    }
}

// ---------------- fallback (fp32 direct) if workspace too small ----------
__global__ __launch_bounds__(256) void attn_fwd_v1(
    const float* __restrict__ q, const float* __restrict__ kk,
    const float* __restrict__ v, float* __restrict__ out)
{
    const int tid  = threadIdx.x;
    const int lane = tid & 63;
    const int w    = tid >> 6;
    const int lo   = lane & 15;
    const int hi   = lane >> 4;
    const int qt   = blockIdx.x;
    const int h    = blockIdx.y;
    const int b    = blockIdx.z;

    __shared__ __align__(16) __bf16 p_lds[4][16][40];

    const size_t bh_off = (size_t)b * N_ * HD + (size_t)h * D_;
    const float* qp = q + bh_off;
    const float* kp = kk + bh_off;
    const float* vp = v + bh_off;
    float*       op = out + bh_off;

    const int q0 = qt * 64 + w * 16;

    bf16x8 qa[2];
    {
        const float* qrow = qp + (size_t)(q0 + lo) * HD + hi * 8;
        #pragma unroll
        for (int kx = 0; kx < 2; ++kx)
            #pragma unroll
            for (int j = 0; j < 8; ++j)
                qa[kx][j] = (__bf16)(qrow[kx * 32 + j] * 0.125f);
    }

    float m[4], l[4];
    f32x4 o[4];
    #pragma unroll
    for (int r = 0; r < 4; ++r) { m[r] = -INFINITY; l[r] = 0.f; }
    #pragma unroll
    for (int f = 0; f < 4; ++f) o[f] = (f32x4)0.f;

    for (int kv0 = 0; kv0 < N_; kv0 += 32) {
        f32x4 s[2];
        #pragma unroll
        for (int c = 0; c < 2; ++c) {
            s[c] = (f32x4)0.f;
            const float* krow = kp + (size_t)(kv0 + c * 16 + lo) * HD + hi * 8;
            #pragma unroll
            for (int kx = 0; kx < 2; ++kx) {
                bf16x8 kbv;
                #pragma unroll
                for (int j = 0; j < 8; ++j) kbv[j] = (__bf16)krow[kx * 32 + j];
                s[c] = __builtin_amdgcn_mfma_f32_16x16x32_bf16(qa[kx], kbv, s[c], 0, 0, 0);
            }
        }
        float alpha[4], p0[4], p1[4];
        #pragma unroll
        for (int r = 0; r < 4; ++r) {
            float t = fmaxf(s[0][r], s[1][r]);
            #pragma unroll
            for (int msk = 1; msk <= 8; msk <<= 1) t = fmaxf(t, __shfl_xor(t, msk, 64));
            float mn = fmaxf(m[r], t);
            alpha[r] = __expf(m[r] - mn);
            p0[r] = __expf(s[0][r] - mn);
            p1[r] = __expf(s[1][r] - mn);
            float rs = p0[r] + p1[r];
            #pragma unroll
            for (int msk = 1; msk <= 8; msk <<= 1) rs += __shfl_xor(rs, msk, 64);
            l[r] = l[r] * alpha[r] + rs;
            m[r] = mn;
        }
        #pragma unroll
        for (int f = 0; f < 4; ++f)
            #pragma unroll
            for (int r = 0; r < 4; ++r) o[f][r] *= alpha[r];
        #pragma unroll
        for (int r = 0; r < 4; ++r) {
            p_lds[w][hi * 4 + r][lo]      = (__bf16)p0[r];
            p_lds[w][hi * 4 + r][16 + lo] = (__bf16)p1[r];
        }
        __syncthreads();
        bf16x8 pa = *(const bf16x8*)&p_lds[w][lo][hi * 8];
        #pragma unroll
        for (int f = 0; f < 4; ++f) {
            const float* vrow = vp + (size_t)(kv0 + hi * 8) * HD + f * 16 + lo;
            bf16x8 vb;
            #pragma unroll
            for (int j = 0; j < 8; ++j) vb[j] = (__bf16)vrow[(size_t)j * HD];
            o[f] = __builtin_amdgcn_mfma_f32_16x16x32_bf16(pa, vb, o[f], 0, 0, 0);
        }
        __syncthreads();
    }
    #pragma unroll
    for (int r = 0; r < 4; ++r) {
        float rinv = 1.f / l[r];
        float* orow = op + (size_t)(q0 + hi * 4 + r) * HD;
        #pragma unroll
        for (int f = 0; f < 4; ++f) orow[f * 16 + lo] = o[f][r] * rinv;
    }
}

extern "C" void kernel_launch(void* const* d_in, const int* in_sizes, int n_in,
                              void* d_out, int out_size, void* d_ws, size_t ws_size,
                              hipStream_t stream)
{
    const float* q = (const float*)d_in[0];
    const float* k = (const float*)d_in[1];
    const float* v = (const float*)d_in[2];
    float* out = (float*)d_out;

    if (ws_size >= WS_NEED) {
        char* ws = (char*)d_ws;
        prep_v<<<dim3(1024), 256, 0, stream>>>(v, ws);
        attn_fwd_v6<<<dim3(256), 512, 0, stream>>>(q, k, ws, out);
    } else {
        attn_fwd_v1<<<dim3(N_ / 64, H_, B_), 256, 0, stream>>>(q, k, v, out);
    }
}